// Round 1
// baseline (210.975 us; speedup 1.0000x reference)
//
#include <hip/hip_runtime.h>
#include <cstdint>
#include <cmath>

#define QP    127.0f
#define MINR  1e-6f

// Problem dims (from setup_inputs): B*N = 8192 tokens, D = 1024, H = 4096
#define MTOK 8192
#define DDIM 1024
#define HDIM 4096

typedef __attribute__((ext_vector_type(4))) int int32x4;

__device__ __forceinline__ void gload16(const void* g, void* l) {
    __builtin_amdgcn_global_load_lds(
        (const __attribute__((address_space(1))) void*)g,
        (__attribute__((address_space(3))) void*)l, 16, 0, 0);
}

__global__ void zero_scales_kernel(float* g) {
    if (threadIdx.x < 4) g[threadIdx.x] = 0.0f;
}

// max |in| over n4 float4s -> atomicMax(int-bits) into *gout (nonneg floats)
__global__ void absmax_kernel(const float* __restrict__ in, int n4, float* __restrict__ gout) {
    const float4* in4 = (const float4*)in;
    int tid = blockIdx.x * blockDim.x + threadIdx.x;
    int stride = gridDim.x * blockDim.x;
    float m = 0.0f;
    for (int i = tid; i < n4; i += stride) {
        float4 v = in4[i];
        m = fmaxf(m, fmaxf(fmaxf(fabsf(v.x), fabsf(v.y)), fmaxf(fabsf(v.z), fabsf(v.w))));
    }
    #pragma unroll
    for (int off = 32; off; off >>= 1) m = fmaxf(m, __shfl_down(m, off));
    __shared__ float sm[4];
    int lane = threadIdx.x & 63, w = threadIdx.x >> 6;
    if (lane == 0) sm[w] = m;
    __syncthreads();
    if (threadIdx.x == 0) {
        float bm = fmaxf(fmaxf(sm[0], sm[1]), fmaxf(sm[2], sm[3]));
        atomicMax((int*)gout, __float_as_int(bm));
    }
}

// out[i] = int8(rint(in[i] / scale)), scale = max(*gm,1e-6)/127  (exact fp32 div, RNE)
__global__ void quant_kernel(const float* __restrict__ in, int8_t* __restrict__ out,
                             int n4, const float* __restrict__ gm) {
    const float s = fmaxf(*gm, MINR) / QP;
    const float4* in4 = (const float4*)in;
    int* out4 = (int*)out;
    int tid = blockIdx.x * blockDim.x + threadIdx.x;
    int stride = gridDim.x * blockDim.x;
    for (int i = tid; i < n4; i += stride) {
        float4 v = in4[i];
        int q0 = ((int)rintf(v.x / s)) & 255;
        int q1 = ((int)rintf(v.y / s)) & 255;
        int q2 = ((int)rintf(v.z / s)) & 255;
        int q3 = ((int)rintf(v.w / s)) & 255;
        out4[i] = q0 | (q1 << 8) | (q2 << 16) | (q3 << 24);
    }
}

// C = A(i8)[Mx KD] @ B(i8)[ND x KD]^T  (both row-major, K contiguous)
// epilogue: f = (float(acc) + bias[col]) * (sB*sA);  GELU_EPI: out=gelu(f) + absmax reduce
// 128x128 tile, BK=128 bytes, 4 waves, mfma_i32_16x16x64_i8
// LDS: linear-dest global_load_lds with pre-swizzled source; reads XOR-swizzle slot^=(row&7)
template<int KD, int ND, bool GELU_EPI>
__global__ __launch_bounds__(256, 2)
void gemm_i8_kernel(const int8_t* __restrict__ A, const int8_t* __restrict__ B,
                    const float* __restrict__ bias,
                    const float* __restrict__ gmA, const float* __restrict__ gmB,
                    float* __restrict__ out, float* __restrict__ omax) {
    __shared__ int8_t lA[128 * 128];
    __shared__ int8_t lB[128 * 128];
    const int t = threadIdx.x;
    const int lane = t & 63;
    const int w = t >> 6;
    const int wm = (w >> 1) * 64;   // wave row offset in tile
    const int wn = (w & 1) * 64;    // wave col offset in tile
    const int lr = lane & 15;
    const int lg = lane >> 4;       // 0..3
    const int br = blockIdx.y, bc = blockIdx.x;

    const int8_t* Ab = A + (size_t)br * 128 * KD;
    const int8_t* Bb = B + (size_t)bc * 128 * KD;

    int32x4 acc[4][4] = {};

    for (int kt = 0; kt < KD / 128; ++kt) {
        // stage 16KB A + 16KB B: 1024 chunks of 16B each, linear LDS dest,
        // source column slot pre-swizzled by (row&7) so LDS holds swizzled layout
        #pragma unroll
        for (int i = 0; i < 4; ++i) {
            int c = t + i * 256;          // 0..1023
            int r = c >> 3;               // tile row 0..127
            int sl = c & 7;               // 16B slot 0..7
            int sc = ((sl ^ (r & 7)) << 4);
            gload16(Ab + (size_t)r * KD + kt * 128 + sc, &lA[c * 16]);
            gload16(Bb + (size_t)r * KD + kt * 128 + sc, &lB[c * 16]);
        }
        __syncthreads();   // compiler emits vmcnt(0)+lgkmcnt(0) drain before barrier

        #pragma unroll
        for (int kk = 0; kk < 2; ++kk) {
            int32x4 af[4], bf[4];
            #pragma unroll
            for (int m = 0; m < 4; ++m) {
                int r = wm + m * 16 + lr;
                int g = kk * 4 + lg;
                af[m] = *(const int32x4*)&lA[r * 128 + ((g ^ (r & 7)) << 4)];
            }
            #pragma unroll
            for (int n = 0; n < 4; ++n) {
                int r = wn + n * 16 + lr;
                int g = kk * 4 + lg;
                bf[n] = *(const int32x4*)&lB[r * 128 + ((g ^ (r & 7)) << 4)];
            }
            #pragma unroll
            for (int m = 0; m < 4; ++m)
                #pragma unroll
                for (int n = 0; n < 4; ++n)
                    acc[m][n] = __builtin_amdgcn_mfma_i32_16x16x64_i8(af[m], bf[n], acc[m][n], 0, 0, 0);
        }
        __syncthreads();
    }

    // epilogue — replicate reference fp32 op order exactly:
    // scale = max(g,1e-6)/127 (fp32 div); out = (int_matmul + bias) * (sw*sx)
    const float sA = fmaxf(*gmA, MINR) / QP;
    const float sB = fmaxf(*gmB, MINR) / QP;
    const float s = sB * sA;
    float lmax = 0.0f;
    #pragma unroll
    for (int m = 0; m < 4; ++m) {
        #pragma unroll
        for (int n = 0; n < 4; ++n) {
            #pragma unroll
            for (int r = 0; r < 4; ++r) {
                int row = br * 128 + wm + m * 16 + lg * 4 + r;
                int col = bc * 128 + wn + n * 16 + lr;
                float f = (float)acc[m][n][r] + bias[col];
                f *= s;
                if (GELU_EPI) {
                    // jax.nn.gelu exact: x * (erf(x/sqrt(2)) + 1) / 2
                    float gg = f * (erff(f / 1.41421356237309504880f) + 1.0f) * 0.5f;
                    out[(size_t)row * ND + col] = gg;
                    lmax = fmaxf(lmax, fabsf(gg));
                } else {
                    out[(size_t)row * ND + col] = f;
                }
            }
        }
    }
    if (GELU_EPI) {
        #pragma unroll
        for (int off = 32; off; off >>= 1) lmax = fmaxf(lmax, __shfl_down(lmax, off));
        __shared__ float red[4];
        if (lane == 0) red[w] = lmax;
        __syncthreads();
        if (t == 0) {
            float bm = fmaxf(fmaxf(red[0], red[1]), fmaxf(red[2], red[3]));
            atomicMax((int*)omax, __float_as_int(bm));
        }
    }
}

extern "C" void kernel_launch(void* const* d_in, const int* in_sizes, int n_in,
                              void* d_out, int out_size, void* d_ws, size_t ws_size,
                              hipStream_t stream) {
    const float* x  = (const float*)d_in[0];   // [8192, 1024]
    const float* w1 = (const float*)d_in[1];   // [4096, 1024]
    const float* b1 = (const float*)d_in[2];   // [4096]
    const float* w2 = (const float*)d_in[3];   // [1024, 4096]
    const float* b2 = (const float*)d_in[4];   // [1024]
    float* out = (float*)d_out;                // [8192, 1024]

    uint8_t* ws = (uint8_t*)d_ws;
    float*  gmax = (float*)ws;                           // [0]=x, [1]=w1, [2]=h, [3]=w2
    int8_t* xq   = (int8_t*)(ws + 256);                  // 8 MiB
    int8_t* w1q  = xq  + (size_t)MTOK * DDIM;            // 4 MiB
    int8_t* w2q  = w1q + (size_t)HDIM * DDIM;            // 4 MiB
    int8_t* hq   = w2q + (size_t)DDIM * HDIM;            // 32 MiB
    float*  h    = (float*)(hq + (size_t)MTOK * HDIM);   // 128 MiB fp32

    zero_scales_kernel<<<1, 64, 0, stream>>>(gmax);

    absmax_kernel<<<1024, 256, 0, stream>>>(x,  MTOK * DDIM / 4, gmax + 0);
    absmax_kernel<<<512,  256, 0, stream>>>(w1, HDIM * DDIM / 4, gmax + 1);
    absmax_kernel<<<512,  256, 0, stream>>>(w2, DDIM * HDIM / 4, gmax + 3);

    quant_kernel<<<2048, 256, 0, stream>>>(x,  xq,  MTOK * DDIM / 4, gmax + 0);
    quant_kernel<<<1024, 256, 0, stream>>>(w1, w1q, HDIM * DDIM / 4, gmax + 1);
    quant_kernel<<<1024, 256, 0, stream>>>(w2, w2q, DDIM * HDIM / 4, gmax + 3);

    // h = gelu((xq @ w1q^T + b1) * s1), fused absmax(h) -> gmax[2]
    gemm_i8_kernel<DDIM, HDIM, true>
        <<<dim3(HDIM / 128, MTOK / 128), 256, 0, stream>>>(xq, w1q, b1, gmax + 0, gmax + 1, h, gmax + 2);

    quant_kernel<<<4096, 256, 0, stream>>>(h, hq, MTOK * HDIM / 4, gmax + 2);

    // out = (hq @ w2q^T + b2) * s2
    gemm_i8_kernel<HDIM, DDIM, false>
        <<<dim3(DDIM / 128, MTOK / 128), 256, 0, stream>>>(hq, w2q, b2, gmax + 2, gmax + 3, out, nullptr);
}